// Round 3
// baseline (1328.565 us; speedup 1.0000x reference)
//
#include <hip/hip_runtime.h>
#include <hip/hip_bf16.h>

#define D_  1536
#define H_  16
#define HD_ 96
#define NX_ 2048
#define NY_ 256
#define NT_ 2304
#define FF_ 6144
#define EPS_ 1e-6f

typedef unsigned short u16;
typedef unsigned int   u32;
typedef short short8 __attribute__((ext_vector_type(8)));
typedef float f32x4  __attribute__((ext_vector_type(4)));

__device__ __forceinline__ u16 f2bf(float f){
    u32 u = __float_as_uint(f);
    return (u16)((u + 0x7fffu + ((u >> 16) & 1u)) >> 16);   // RNE
}
__device__ __forceinline__ float bf2f(u16 h){ return __uint_as_float(((u32)h) << 16); }

// ---------------------------------------------------------------- mod GEMV
// st = silu(t); modx = st @ w_mod_x + b_mod_x ; mody likewise. 72 blocks x 256.
__global__ __launch_bounds__(256) void modvec_k(
    const float* __restrict__ t_in,
    const float* __restrict__ w_mod_x, const float* __restrict__ b_mod_x,
    const float* __restrict__ w_mod_y, const float* __restrict__ b_mod_y,
    float* __restrict__ modx, float* __restrict__ mody)
{
    __shared__ float st[D_];
    int tid = threadIdx.x;
    for (int k = tid; k < D_; k += 256){
        float v = t_in[k];
        st[k] = v / (1.f + __expf(-v));
    }
    __syncthreads();
    int j = blockIdx.x * 256 + tid;          // 0..18431
    const float* W; const float* bb; float* out; int col;
    if (j < 6*D_){ W = w_mod_x; bb = b_mod_x; out = modx; col = j; }
    else         { W = w_mod_y; bb = b_mod_y; out = mody; col = j - 6*D_; }
    float acc = bb[col];
    for (int k = 0; k < D_; k++)
        acc += st[k] * W[(size_t)k * (6*D_) + col];
    out[col] = acc;
}

// ---------------------------------------------------------------- LN + modulate -> bf16
// rows 0..2047 from inx (stream x mods), rows 2048..2303 from iny (stream y mods)
__global__ __launch_bounds__(256) void lnmod_k(
    const float* __restrict__ inx, const float* __restrict__ iny,
    const float* __restrict__ modx, const float* __restrict__ mody,
    int shoff, u16* __restrict__ out)
{
    int row = blockIdx.x, t = threadIdx.x;
    const float* in; const float* mod;
    if (row < NX_){ in = inx + (size_t)row * D_;        mod = modx; }
    else          { in = iny + (size_t)(row-NX_) * D_;  mod = mody; }
    const float* sh = mod + shoff;
    const float* sc = mod + shoff + D_;
    float vals[6]; float s = 0.f, ss = 0.f;
    #pragma unroll
    for (int j = 0; j < 6; j++){
        float v = in[t + j*256];
        vals[j] = v; s += v; ss += v*v;
    }
    for (int mask = 1; mask < 64; mask <<= 1){
        s  += __shfl_xor(s,  mask);
        ss += __shfl_xor(ss, mask);
    }
    __shared__ float red[2][4];
    int wave = t >> 6, lane = t & 63;
    if (lane == 0){ red[0][wave] = s; red[1][wave] = ss; }
    __syncthreads();
    s  = red[0][0] + red[0][1] + red[0][2] + red[0][3];
    ss = red[1][0] + red[1][1] + red[1][2] + red[1][3];
    float mean = s * (1.f / D_);
    float var  = ss * (1.f / D_) - mean * mean;
    float inv  = rsqrtf(var + EPS_);
    #pragma unroll
    for (int j = 0; j < 6; j++){
        int c = t + j*256;
        float z = (vals[j] - mean) * inv;
        z = z * (1.f + sc[c]) + sh[c];
        out[(size_t)row * D_ + c] = f2bf(z);
    }
}

// ---------------------------------------------------------------- GEMM 128x128, BK=32
// A bf16 (MxK), B f32 (KxN) converted on the fly. 4 waves, 16x16x32 MFMA.
// MODE 0: outF = acc + bias                         (qkv)
// MODE 1: outF = resid + gmod[c]*(acc + bias[c])    (proj -> x1)
// MODE 2: outB = bf16(silu(acc))                    (ffn w1 -> hs)
// MODE 3: outB = bf16(bf2f(hmul)*acc)               (ffn w2 -> hb)
// MODE 4: outF = resid + gmod[c]*acc                (ffn w3 -> d_out)
template<int MODE>
__global__ __launch_bounds__(256) void gemm_k(
    const u16* __restrict__ A, int lda,
    const float* __restrict__ B, int ldb,
    const float* __restrict__ bias,
    const float* __restrict__ resid,
    const float* __restrict__ gmod,
    const u16* __restrict__ hmul,
    float* __restrict__ outF, u16* __restrict__ outB, int ldo,
    int K, int mblocks)
{
    __shared__ u16 As[128][40];   // stride 80B: 16B-aligned, 2-way banked
    __shared__ u16 Bs[128][40];   // transposed: Bs[n][k]
    int bid = blockIdx.x;
    int bm = bid % mblocks, bn = bid / mblocks;
    int row0 = bm * 128, col0 = bn * 128;
    int t = threadIdx.x;
    int wave = t >> 6, lane = t & 63, lrow = lane & 15, lgrp = lane >> 4;
    int wr = (wave >> 1) * 64, wc = (wave & 1) * 64;

    f32x4 acc[4][4];
    #pragma unroll
    for (int i = 0; i < 4; i++)
        #pragma unroll
        for (int j = 0; j < 4; j++) acc[i][j] = (f32x4){0.f,0.f,0.f,0.f};

    int ar = t >> 1, ac = (t & 1) * 16;
    const u16* aptr = A + (size_t)(row0 + ar) * lda + ac;
    int bn_ = t & 127, bkg = (t >> 7) * 16;
    const float* bptr = B + (size_t)bkg * ldb + col0 + bn_;

    for (int k0 = 0; k0 < K; k0 += 32){
        __syncthreads();
        // stage A (bf16, vector)
        uint4 av0 = *(const uint4*)(aptr);
        uint4 av1 = *(const uint4*)(aptr + 8);
        *(uint4*)&As[ar][ac]     = av0;
        *(uint4*)&As[ar][ac + 8] = av1;
        // stage B (f32 -> bf16, transposed into Bs[n][k])
        float bv[16];
        #pragma unroll
        for (int j = 0; j < 16; j++) bv[j] = bptr[(size_t)j * ldb];
        u32 pk[8];
        #pragma unroll
        for (int j = 0; j < 8; j++)
            pk[j] = (u32)f2bf(bv[2*j]) | ((u32)f2bf(bv[2*j+1]) << 16);
        uint4 w0; w0.x = pk[0]; w0.y = pk[1]; w0.z = pk[2]; w0.w = pk[3];
        uint4 w1; w1.x = pk[4]; w1.y = pk[5]; w1.z = pk[6]; w1.w = pk[7];
        *(uint4*)&Bs[bn_][bkg]     = w0;
        *(uint4*)&Bs[bn_][bkg + 8] = w1;
        aptr += 32; bptr += (size_t)32 * ldb;
        __syncthreads();

        short8 af[4], bf[4];
        #pragma unroll
        for (int mi = 0; mi < 4; mi++)
            af[mi] = *(const short8*)&As[wr + mi*16 + lrow][lgrp*8];
        #pragma unroll
        for (int ni = 0; ni < 4; ni++)
            bf[ni] = *(const short8*)&Bs[wc + ni*16 + lrow][lgrp*8];
        #pragma unroll
        for (int mi = 0; mi < 4; mi++)
            #pragma unroll
            for (int ni = 0; ni < 4; ni++)
                acc[mi][ni] = __builtin_amdgcn_mfma_f32_16x16x32_bf16(
                                  af[mi], bf[ni], acc[mi][ni], 0, 0, 0);
    }

    #pragma unroll
    for (int mi = 0; mi < 4; mi++){
        #pragma unroll
        for (int ni = 0; ni < 4; ni++){
            #pragma unroll
            for (int r = 0; r < 4; r++){
                int gr = row0 + wr + mi*16 + lgrp*4 + r;   // row = 4*(lane>>4)+reg
                int gc = col0 + wc + ni*16 + lrow;         // col = lane&15
                float v = acc[mi][ni][r];
                size_t oi = (size_t)gr * ldo + gc;
                if (MODE == 0)      outF[oi] = v + bias[gc];
                else if (MODE == 1) outF[oi] = resid[oi] + gmod[gc] * (v + bias[gc]);
                else if (MODE == 2) outB[oi] = f2bf(v / (1.f + __expf(-v)));
                else if (MODE == 3) outB[oi] = f2bf(bf2f(hmul[oi]) * v);
                else if (MODE == 4) outF[oi] = resid[oi] + gmod[gc] * v;
            }
        }
    }
}

// ---------------------------------------------------------------- qkv postprocess
// qkvraw f32 [tok][4608] -> per-head RMS(+weight) + RoPE(x only, last 48) -> bf16
// Q/K/V laid out [h][tok][96]. One block per token; wave handles 4 heads.
__global__ __launch_bounds__(256) void qkvpost_k(
    const float* __restrict__ qkvraw, const int* __restrict__ positions,
    const float* __restrict__ qn_x, const float* __restrict__ kn_x,
    const float* __restrict__ qn_y, const float* __restrict__ kn_y,
    u16* __restrict__ Qg, u16* __restrict__ Kg, u16* __restrict__ Vg)
{
    int tok = blockIdx.x;
    int t = threadIdx.x, wave = t >> 6, lane = t & 63;
    bool isx = tok < NX_;
    float pos = isx ? (float)positions[tok] : 0.f;
    const float* qn = isx ? qn_x : qn_y;
    const float* kn = isx ? kn_x : kn_y;
    bool act = lane < 48;
    int d = lane * 2;
    #pragma unroll
    for (int hh = 0; hh < 4; hh++){
        int h = wave + hh * 4;
        const float* base = qkvraw + (size_t)tok * (3*D_) + h * HD_;
        float qx=0.f,qy=0.f,kx=0.f,ky=0.f,vx=0.f,vy=0.f;
        if (act){
            float2 q2 = *(const float2*)(base + d);
            float2 k2 = *(const float2*)(base + D_ + d);
            float2 v2 = *(const float2*)(base + 2*D_ + d);
            qx=q2.x; qy=q2.y; kx=k2.x; ky=k2.y; vx=v2.x; vy=v2.y;
        }
        float sq = qx*qx + qy*qy, sk = kx*kx + ky*ky;
        for (int mask = 1; mask < 64; mask <<= 1){
            sq += __shfl_xor(sq, mask);
            sk += __shfl_xor(sk, mask);
        }
        float rq = rsqrtf(sq / (float)HD_ + EPS_);
        float rk = rsqrtf(sk / (float)HD_ + EPS_);
        if (act){
            qx *= rq * qn[d]; qy *= rq * qn[d+1];
            kx *= rk * kn[d]; ky *= rk * kn[d+1];
        }
        // RoPE partners (pair (i, i+24) inside the last-48 block)
        int pl = (lane < 36) ? lane + 12 : lane - 12;
        float qpx = __shfl(qx, pl), qpy = __shfl(qy, pl);
        float kpx = __shfl(kx, pl), kpy = __shfl(ky, pl);
        if (isx && lane >= 24 && act){
            bool aside = lane < 36;
            int i0 = aside ? (2*lane - 48) : (2*lane - 72);
            float ang0 = pos * __powf(10000.f, -(float)i0 / 24.f);
            float ang1 = pos * __powf(10000.f, -(float)(i0+1) / 24.f);
            float s0,c0,s1,c1;
            __sincosf(ang0, &s0, &c0);
            __sincosf(ang1, &s1, &c1);
            if (aside){
                qx = qx*c0 - qpx*s0;  qy = qy*c1 - qpy*s1;
                kx = kx*c0 - kpx*s0;  ky = ky*c1 - kpy*s1;
            } else {
                qx = qx*c0 + qpx*s0;  qy = qy*c1 + qpy*s1;
                kx = kx*c0 + kpx*s0;  ky = ky*c1 + kpy*s1;
            }
        }
        if (act){
            size_t o = ((size_t)h * NT_ + tok) * HD_ + d;
            Qg[o] = f2bf(qx); Qg[o+1] = f2bf(qy);
            Kg[o] = f2bf(kx); Kg[o+1] = f2bf(ky);
            Vg[o] = f2bf(vx); Vg[o+1] = f2bf(vy);
        }
    }
}

// ---------------------------------------------------------------- flash attention
// grid (36 qblocks, 16 heads), 256 thr. 64 Q-rows/block (16/wave), K/V tiles of 64.
__global__ __launch_bounds__(256) void attn_k(
    const u16* __restrict__ Qg, const u16* __restrict__ Kg,
    const u16* __restrict__ Vg, u16* __restrict__ Og)
{
    int h = blockIdx.y;
    int q0 = blockIdx.x * 64;
    __shared__ u16 Ks[64][104];     // row stride 208B (16B-aligned)
    __shared__ u16 Vt[96][72];      // V transposed: Vt[n][k], stride 144B
    __shared__ u16 Ps[4][16][72];   // per-wave P tile
    int t = threadIdx.x, wave = t >> 6, lane = t & 63;
    int lrow = lane & 15, lgrp = lane >> 4;
    const float scale = 0.10206207261596577f;   // 96^-0.5

    const u16* qbase = Qg + ((size_t)h * NT_ + q0 + wave*16 + lrow) * HD_;
    short8 qf[3];
    #pragma unroll
    for (int c = 0; c < 3; c++) qf[c] = *(const short8*)(qbase + c*32 + lgrp*8);

    float mr[4], lr[4];
    #pragma unroll
    for (int r = 0; r < 4; r++){ mr[r] = -1e30f; lr[r] = 0.f; }
    f32x4 oacc[6];
    #pragma unroll
    for (int n = 0; n < 6; n++) oacc[n] = (f32x4){0.f,0.f,0.f,0.f};

    int sr = t >> 2, sc4 = (t & 3) * 24;
    for (int kt = 0; kt < NT_/64; kt++){
        __syncthreads();
        {
            const u16* kp = Kg + ((size_t)h * NT_ + kt*64 + sr) * HD_ + sc4;
            uint4 a0 = *(const uint4*)kp;
            uint4 a1 = *(const uint4*)(kp + 8);
            uint4 a2 = *(const uint4*)(kp + 16);
            *(uint4*)&Ks[sr][sc4]      = a0;
            *(uint4*)&Ks[sr][sc4 + 8]  = a1;
            *(uint4*)&Ks[sr][sc4 + 16] = a2;
            const u16* vp = Vg + ((size_t)h * NT_ + kt*64 + sr) * HD_ + sc4;
            u16 vv[24];
            *(uint4*)&vv[0]  = *(const uint4*)vp;
            *(uint4*)&vv[8]  = *(const uint4*)(vp + 8);
            *(uint4*)&vv[16] = *(const uint4*)(vp + 16);
            #pragma unroll
            for (int j = 0; j < 24; j++) Vt[sc4 + j][sr] = vv[j];
        }
        __syncthreads();

        f32x4 s[4];
        #pragma unroll
        for (int nt = 0; nt < 4; nt++){
            s[nt] = (f32x4){0.f,0.f,0.f,0.f};
            #pragma unroll
            for (int c = 0; c < 3; c++){
                short8 kf = *(const short8*)&Ks[nt*16 + lrow][c*32 + lgrp*8];
                s[nt] = __builtin_amdgcn_mfma_f32_16x16x32_bf16(qf[c], kf, s[nt], 0,0,0);
            }
        }
        #pragma unroll
        for (int nt = 0; nt < 4; nt++) s[nt] *= scale;

        float mnew[4], corr[4];
        #pragma unroll
        for (int r = 0; r < 4; r++){
            float mt = fmaxf(fmaxf(s[0][r], s[1][r]), fmaxf(s[2][r], s[3][r]));
            for (int mask = 1; mask < 16; mask <<= 1)
                mt = fmaxf(mt, __shfl_xor(mt, mask));
            mnew[r] = fmaxf(mr[r], mt);
            corr[r] = __expf(mr[r] - mnew[r]);
            mr[r] = mnew[r];
        }
        float rs[4] = {0.f,0.f,0.f,0.f};
        #pragma unroll
        for (int nt = 0; nt < 4; nt++){
            #pragma unroll
            for (int r = 0; r < 4; r++){
                float p = __expf(s[nt][r] - mnew[r]);
                rs[r] += p;
                Ps[wave][lgrp*4 + r][nt*16 + lrow] = f2bf(p);
            }
        }
        #pragma unroll
        for (int r = 0; r < 4; r++){
            for (int mask = 1; mask < 16; mask <<= 1)
                rs[r] += __shfl_xor(rs[r], mask);
            lr[r] = lr[r] * corr[r] + rs[r];
        }
        #pragma unroll
        for (int n = 0; n < 6; n++)
            #pragma unroll
            for (int r = 0; r < 4; r++) oacc[n][r] *= corr[r];

        #pragma unroll
        for (int kc = 0; kc < 2; kc++){
            short8 pf = *(const short8*)&Ps[wave][lrow][kc*32 + lgrp*8];
            #pragma unroll
            for (int n = 0; n < 6; n++){
                short8 vf = *(const short8*)&Vt[n*16 + lrow][kc*32 + lgrp*8];
                oacc[n] = __builtin_amdgcn_mfma_f32_16x16x32_bf16(pf, vf, oacc[n], 0,0,0);
            }
        }
    }

    #pragma unroll
    for (int n = 0; n < 6; n++){
        #pragma unroll
        for (int r = 0; r < 4; r++){
            int tok = q0 + wave*16 + lgrp*4 + r;
            float ov = oacc[n][r] / lr[r];
            Og[(size_t)tok * D_ + h*HD_ + n*16 + lrow] = f2bf(ov);
        }
    }
}

// ---------------------------------------------------------------- launcher
extern "C" void kernel_launch(void* const* d_in, const int* in_sizes, int n_in,
                              void* d_out, int out_size, void* d_ws, size_t ws_size,
                              hipStream_t stream)
{
    const float* x        = (const float*)d_in[0];
    const float* y        = (const float*)d_in[1];
    const float* tt       = (const float*)d_in[2];
    const int*   pos      = (const int*)  d_in[3];
    const float* w_mod_x  = (const float*)d_in[4];
    const float* b_mod_x  = (const float*)d_in[5];
    const float* w_mod_y  = (const float*)d_in[6];
    const float* b_mod_y  = (const float*)d_in[7];
    const float* w_qkv_x  = (const float*)d_in[8];
    const float* b_qkv_x  = (const float*)d_in[9];
    const float* w_qkv_y  = (const float*)d_in[10];
    const float* b_qkv_y  = (const float*)d_in[11];
    const float* qn_x     = (const float*)d_in[12];
    const float* kn_x     = (const float*)d_in[13];
    const float* qn_y     = (const float*)d_in[14];
    const float* kn_y     = (const float*)d_in[15];
    const float* w_proj_x = (const float*)d_in[16];
    const float* b_proj_x = (const float*)d_in[17];
    const float* w_proj_y = (const float*)d_in[18];
    const float* b_proj_y = (const float*)d_in[19];
    const float* w1_x     = (const float*)d_in[20];
    const float* w2_x     = (const float*)d_in[21];
    const float* w3_x     = (const float*)d_in[22];
    const float* w1_y     = (const float*)d_in[23];
    const float* w2_y     = (const float*)d_in[24];
    const float* w3_y     = (const float*)d_in[25];
    float* dout = (float*)d_out;

    char* ws = (char*)d_ws;
    size_t off = 0;
    float* modx   = (float*)(ws + off); off += (size_t)(6*D_) * 4;
    float* mody   = (float*)(ws + off); off += (size_t)(6*D_) * 4;
    u16*   a      = (u16*)  (ws + off); off += (size_t)NT_ * D_ * 2;
    size_t qkvraw_off = off;
    float* qkvraw = (float*)(ws + off); off += (size_t)NT_ * (3*D_) * 4;
    u16*   Qb     = (u16*)  (ws + off); off += (size_t)H_ * NT_ * HD_ * 2;
    u16*   Kb     = (u16*)  (ws + off); off += (size_t)H_ * NT_ * HD_ * 2;
    u16*   Vb     = (u16*)  (ws + off); off += (size_t)H_ * NT_ * HD_ * 2;
    u16*   Ob     = (u16*)  (ws + off); off += (size_t)NT_ * D_ * 2;
    float* x1     = (float*)(ws + off); off += (size_t)NT_ * D_ * 4;
    u16*   hs     = (u16*)(ws + qkvraw_off);  // reuse (qkvraw dead after postproc)
    u16*   hb     = Qb;                       // spans Qb..Ob = exactly NT_*FF_*2 bytes

    // 1) modulation vectors
    modvec_k<<<72, 256, 0, stream>>>(tt, w_mod_x, b_mod_x, w_mod_y, b_mod_y, modx, mody);
    // 2) LN + mod1 -> a (bf16)
    lnmod_k<<<NT_, 256, 0, stream>>>(x, y, modx, mody, 0, a);
    // 3) qkv GEMMs
    gemm_k<0><<<16*36, 256, 0, stream>>>(a, D_, w_qkv_x, 3*D_, b_qkv_x,
        nullptr, nullptr, nullptr, qkvraw, nullptr, 3*D_, D_, 16);
    gemm_k<0><<<2*36, 256, 0, stream>>>(a + (size_t)NX_*D_, D_, w_qkv_y, 3*D_, b_qkv_y,
        nullptr, nullptr, nullptr, qkvraw + (size_t)NX_*(3*D_), nullptr, 3*D_, D_, 2);
    // 4) RMS + RoPE + reshape
    qkvpost_k<<<NT_, 256, 0, stream>>>(qkvraw, pos, qn_x, kn_x, qn_y, kn_y, Qb, Kb, Vb);
    // 5) attention
    attn_k<<<dim3(36, 16), 256, 0, stream>>>(Qb, Kb, Vb, Ob);
    // 6) proj + residual -> x1
    gemm_k<1><<<16*12, 256, 0, stream>>>(Ob, D_, w_proj_x, D_, b_proj_x,
        x, modx + 2*D_, nullptr, x1, nullptr, D_, D_, 16);
    gemm_k<1><<<2*12, 256, 0, stream>>>(Ob + (size_t)NX_*D_, D_, w_proj_y, D_, b_proj_y,
        y, mody + 2*D_, nullptr, x1 + (size_t)NX_*D_, nullptr, D_, D_, 2);
    // 7) LN + mod2 -> a (bf16)
    lnmod_k<<<NT_, 256, 0, stream>>>(x1, x1 + (size_t)NX_*D_, modx, mody, 3*D_, a);
    // 8) ffn w1 -> silu -> hs
    gemm_k<2><<<16*48, 256, 0, stream>>>(a, D_, w1_x, FF_, nullptr,
        nullptr, nullptr, nullptr, nullptr, hs, FF_, D_, 16);
    gemm_k<2><<<2*48, 256, 0, stream>>>(a + (size_t)NX_*D_, D_, w1_y, FF_, nullptr,
        nullptr, nullptr, nullptr, nullptr, hs + (size_t)NX_*FF_, FF_, D_, 2);
    // 9) ffn w2, multiply by hs -> hb
    gemm_k<3><<<16*48, 256, 0, stream>>>(a, D_, w2_x, FF_, nullptr,
        nullptr, nullptr, hs, nullptr, hb, FF_, D_, 16);
    gemm_k<3><<<2*48, 256, 0, stream>>>(a + (size_t)NX_*D_, D_, w2_y, FF_, nullptr,
        nullptr, nullptr, hs + (size_t)NX_*FF_, nullptr, hb + (size_t)NX_*FF_, FF_, D_, 2);
    // 10) ffn w3 + gate + residual -> d_out
    gemm_k<4><<<16*12, 256, 0, stream>>>(hb, FF_, w3_x, D_, nullptr,
        x1, modx + 5*D_, nullptr, dout, nullptr, D_, FF_, 16);
    gemm_k<4><<<2*12, 256, 0, stream>>>(hb + (size_t)NX_*FF_, FF_, w3_y, D_, nullptr,
        x1 + (size_t)NX_*D_, mody + 5*D_, nullptr, dout + (size_t)NX_*D_, nullptr, D_, FF_, 2);
    (void)in_sizes; (void)n_in; (void)out_size; (void)ws_size;
}

// Round 4
// 709.675 us; speedup vs baseline: 1.8721x; 1.8721x over previous
//
#include <hip/hip_runtime.h>
#include <hip/hip_bf16.h>

#define D_  1536
#define H_  16
#define HD_ 96
#define NX_ 2048
#define NY_ 256
#define NT_ 2304
#define FF_ 6144
#define EPS_ 1e-6f

typedef unsigned short u16;
typedef unsigned int   u32;
typedef short short8 __attribute__((ext_vector_type(8)));
typedef float f32x4  __attribute__((ext_vector_type(4)));
typedef unsigned short u16x4 __attribute__((ext_vector_type(4)));

__device__ __forceinline__ u16 f2bf(float f){
    u32 u = __float_as_uint(f);
    return (u16)((u + 0x7fffu + ((u >> 16) & 1u)) >> 16);   // RNE
}
__device__ __forceinline__ float bf2f(u16 h){ return __uint_as_float(((u32)h) << 16); }

__device__ __forceinline__ void gll16(const void* g, void* l){
    __builtin_amdgcn_global_load_lds(
        (const __attribute__((address_space(1))) unsigned int*)g,
        (__attribute__((address_space(3))) unsigned int*)l, 16, 0, 0);
}

// ---------------------------------------------------------------- weight transpose
// W [K][N] f32 -> O [N][K] bf16. One 32x32 tile per block; grid.y selects x/y matrix.
__global__ __launch_bounds__(256) void transpose_k(
    const float* __restrict__ Wx, const float* __restrict__ Wy,
    u16* __restrict__ Ox, u16* __restrict__ Oy, int K, int N)
{
    const float* W = blockIdx.y ? Wy : Wx;
    u16* O = blockIdx.y ? Oy : Ox;
    int tn_cnt = N >> 5;
    int tk = blockIdx.x / tn_cnt, tn = blockIdx.x % tn_cnt;
    __shared__ float tile[32][33];
    int t = threadIdx.x;
    {
        int k = t >> 3, n4 = (t & 7) * 4;
        float4 v = *(const float4*)&W[(size_t)(tk*32 + k) * N + tn*32 + n4];
        tile[k][n4+0] = v.x; tile[k][n4+1] = v.y;
        tile[k][n4+2] = v.z; tile[k][n4+3] = v.w;
    }
    __syncthreads();
    {
        int n = t >> 3, k4 = (t & 7) * 4;
        u16x4 r;
        #pragma unroll
        for (int i = 0; i < 4; i++) r[i] = f2bf(tile[k4+i][n]);
        *(u16x4*)&O[(size_t)(tn*32 + n) * K + tk*32 + k4] = r;
    }
}

// ---------------------------------------------------------------- mod GEMV
__global__ __launch_bounds__(256) void modvec_k(
    const float* __restrict__ t_in,
    const float* __restrict__ w_mod_x, const float* __restrict__ b_mod_x,
    const float* __restrict__ w_mod_y, const float* __restrict__ b_mod_y,
    float* __restrict__ modx, float* __restrict__ mody)
{
    __shared__ float st[D_];
    int tid = threadIdx.x;
    for (int k = tid; k < D_; k += 256){
        float v = t_in[k];
        st[k] = v / (1.f + __expf(-v));
    }
    __syncthreads();
    int j = blockIdx.x * 256 + tid;
    const float* W; const float* bb; float* out; int col;
    if (j < 6*D_){ W = w_mod_x; bb = b_mod_x; out = modx; col = j; }
    else         { W = w_mod_y; bb = b_mod_y; out = mody; col = j - 6*D_; }
    float acc = bb[col];
    for (int k = 0; k < D_; k++)
        acc += st[k] * W[(size_t)k * (6*D_) + col];
    out[col] = acc;
}

// ---------------------------------------------------------------- LN + modulate -> bf16
__global__ __launch_bounds__(256) void lnmod_k(
    const float* __restrict__ inx, const float* __restrict__ iny,
    const float* __restrict__ modx, const float* __restrict__ mody,
    int shoff, u16* __restrict__ out)
{
    int row = blockIdx.x, t = threadIdx.x;
    const float* in; const float* mod;
    if (row < NX_){ in = inx + (size_t)row * D_;        mod = modx; }
    else          { in = iny + (size_t)(row-NX_) * D_;  mod = mody; }
    const float* sh = mod + shoff;
    const float* sc = mod + shoff + D_;
    float vals[6]; float s = 0.f, ss = 0.f;
    #pragma unroll
    for (int j = 0; j < 6; j++){
        float v = in[t + j*256];
        vals[j] = v; s += v; ss += v*v;
    }
    for (int mask = 1; mask < 64; mask <<= 1){
        s  += __shfl_xor(s,  mask);
        ss += __shfl_xor(ss, mask);
    }
    __shared__ float red[2][4];
    int wave = t >> 6, lane = t & 63;
    if (lane == 0){ red[0][wave] = s; red[1][wave] = ss; }
    __syncthreads();
    s  = red[0][0] + red[0][1] + red[0][2] + red[0][3];
    ss = red[1][0] + red[1][1] + red[1][2] + red[1][3];
    float mean = s * (1.f / D_);
    float var  = ss * (1.f / D_) - mean * mean;
    float inv  = rsqrtf(var + EPS_);
    #pragma unroll
    for (int j = 0; j < 6; j++){
        int c = t + j*256;
        float z = (vals[j] - mean) * inv;
        z = z * (1.f + sc[c]) + sh[c];
        out[(size_t)row * D_ + c] = f2bf(z);
    }
}

// ---------------------------------------------------------------- GEMM 128x128, BK=64
// A bf16 [M][K]; BT bf16 [N][K] (pre-transposed weights). 18 M-blocks (16 x + 2 y).
// global_load_lds staging, XOR-swizzled LDS (conflict-free ds_read_b128).
// MODE 0: outB = bf16(acc + bias)                  (qkv -> qkvraw bf16)
// MODE 1: outF = resid + gmod[c]*(acc + bias[c])   (proj -> x1)
// MODE 2: outB = bf16(silu(acc))                   (ffn w1 -> hs)
// MODE 3: outB = bf16(bf2f(hmul)*acc)              (ffn w2 -> hb)
// MODE 4: outF = resid + gmod[c]*acc               (ffn w3 -> out)
template<int MODE>
__global__ __launch_bounds__(256) void gemm2_k(
    const u16* __restrict__ A,
    const u16* __restrict__ BTx, const u16* __restrict__ BTy,
    const float* __restrict__ biasx, const float* __restrict__ biasy,
    const float* __restrict__ residx, const float* __restrict__ residy,
    const float* __restrict__ gmodx, const float* __restrict__ gmody,
    const u16* __restrict__ hmul,
    float* __restrict__ outF, u16* __restrict__ outB, int ldo,
    int K, int nb)
{
    __shared__ u16 As[128*64];
    __shared__ u16 Bs[128*64];
    int nwg = 18 * nb;
    int bid = blockIdx.x;
    int bid2 = (bid & 7) * (nwg >> 3) + (bid >> 3);   // XCD swizzle (8 | nwg)
    int bm = bid2 % 18, bn = bid2 / 18;
    int sel = (bm >= 16);
    int row0 = bm * 128, col0 = bn * 128;
    const u16* Bt = sel ? BTy : BTx;

    int t = threadIdx.x, w = t >> 6, l = t & 63;
    int lrow = l & 15, lgrp = l >> 4;
    int wr = (w >> 1) * 64, wc = (w & 1) * 64;

    // staging: per round i, wave w stages LDS bytes [(i*4+w)*1024, +1024) = 8 rows.
    // lane l -> row r0+(l>>3), physical 16B-chunk p=l&7 holds logical chunk c=p^(r&7).
    const char* Ab = (const char*)(A  + (size_t)row0 * K);
    const char* Bb = (const char*)(Bt + (size_t)col0 * K);
    u32 offA[4], ldsoff[4];
    #pragma unroll
    for (int i = 0; i < 4; i++){
        int r = (i*4 + w)*8 + (l >> 3);
        int c = (l & 7) ^ (r & 7);
        offA[i]   = (u32)(r * K + c * 8) * 2;   // bytes (same for A and BT: both row-length K)
        ldsoff[i] = (u32)((i*4 + w) * 1024);
    }

    f32x4 acc[4][4];
    #pragma unroll
    for (int i = 0; i < 4; i++)
        #pragma unroll
        for (int j = 0; j < 4; j++) acc[i][j] = (f32x4){0.f,0.f,0.f,0.f};

    for (int k0b = 0; k0b < K*2; k0b += 128){   // 64 elements = 128 bytes per step
        __syncthreads();
        #pragma unroll
        for (int i = 0; i < 4; i++) gll16(Ab + (offA[i] + k0b), (char*)As + ldsoff[i]);
        #pragma unroll
        for (int i = 0; i < 4; i++) gll16(Bb + (offA[i] + k0b), (char*)Bs + ldsoff[i]);
        __syncthreads();
        #pragma unroll
        for (int kk = 0; kk < 2; kk++){
            int pc = ((kk*4 + lgrp) ^ (lrow & 7)) * 8;
            short8 af[4], bf[4];
            #pragma unroll
            for (int mi = 0; mi < 4; mi++)
                af[mi] = *(const short8*)&As[(wr + mi*16 + lrow)*64 + pc];
            #pragma unroll
            for (int ni = 0; ni < 4; ni++)
                bf[ni] = *(const short8*)&Bs[(wc + ni*16 + lrow)*64 + pc];
            #pragma unroll
            for (int mi = 0; mi < 4; mi++)
                #pragma unroll
                for (int ni = 0; ni < 4; ni++)
                    acc[mi][ni] = __builtin_amdgcn_mfma_f32_16x16x32_bf16(
                                      af[mi], bf[ni], acc[mi][ni], 0, 0, 0);
        }
    }

    const float* biasp  = sel ? biasy  : biasx;
    const float* residp = sel ? residy : residx;
    const float* gmodp  = sel ? gmody  : gmodx;
    #pragma unroll
    for (int mi = 0; mi < 4; mi++){
        #pragma unroll
        for (int ni = 0; ni < 4; ni++){
            #pragma unroll
            for (int r = 0; r < 4; r++){
                int gr = row0 + wr + mi*16 + lgrp*4 + r;
                int gc = col0 + wc + ni*16 + lrow;
                float v = acc[mi][ni][r];
                size_t oi = (size_t)gr * ldo + gc;
                if (MODE == 0)      outB[oi] = f2bf(v + biasp[gc]);
                else if (MODE == 1) outF[oi] = residp[oi] + gmodp[gc] * (v + biasp[gc]);
                else if (MODE == 2) outB[oi] = f2bf(v / (1.f + __expf(-v)));
                else if (MODE == 3) outB[oi] = f2bf(bf2f(hmul[oi]) * v);
                else if (MODE == 4) outF[oi] = residp[oi] + gmodp[gc] * v;
            }
        }
    }
}

// ---------------------------------------------------------------- qkv postprocess
// qkvraw bf16 [tok][4608] -> per-head RMS + RoPE (x only, last 48) -> bf16 [h][tok][96]
__global__ __launch_bounds__(256) void qkvpost_k(
    const u16* __restrict__ qkvraw, const int* __restrict__ positions,
    const float* __restrict__ qn_x, const float* __restrict__ kn_x,
    const float* __restrict__ qn_y, const float* __restrict__ kn_y,
    u16* __restrict__ Qg, u16* __restrict__ Kg, u16* __restrict__ Vg)
{
    int tok = blockIdx.x;
    int t = threadIdx.x, wave = t >> 6, lane = t & 63;
    bool isx = tok < NX_;
    float pos = isx ? (float)positions[tok] : 0.f;
    const float* qn = isx ? qn_x : qn_y;
    const float* kn = isx ? kn_x : kn_y;
    bool act = lane < 48;
    int d = lane * 2;
    #pragma unroll
    for (int hh = 0; hh < 4; hh++){
        int h = wave + hh * 4;
        const u16* base = qkvraw + (size_t)tok * (3*D_) + h * HD_;
        float qx=0.f,qy=0.f,kx=0.f,ky=0.f,vx=0.f,vy=0.f;
        if (act){
            u32 qw = *(const u32*)(base + d);
            u32 kw = *(const u32*)(base + D_ + d);
            u32 vw = *(const u32*)(base + 2*D_ + d);
            qx = bf2f((u16)qw); qy = bf2f((u16)(qw >> 16));
            kx = bf2f((u16)kw); ky = bf2f((u16)(kw >> 16));
            vx = bf2f((u16)vw); vy = bf2f((u16)(vw >> 16));
        }
        float sq = qx*qx + qy*qy, sk = kx*kx + ky*ky;
        for (int mask = 1; mask < 64; mask <<= 1){
            sq += __shfl_xor(sq, mask);
            sk += __shfl_xor(sk, mask);
        }
        float rq = rsqrtf(sq / (float)HD_ + EPS_);
        float rk = rsqrtf(sk / (float)HD_ + EPS_);
        if (act){
            qx *= rq * qn[d]; qy *= rq * qn[d+1];
            kx *= rk * kn[d]; ky *= rk * kn[d+1];
        }
        int pl = (lane < 36) ? lane + 12 : lane - 12;
        float qpx = __shfl(qx, pl), qpy = __shfl(qy, pl);
        float kpx = __shfl(kx, pl), kpy = __shfl(ky, pl);
        if (isx && lane >= 24 && act){
            bool aside = lane < 36;
            int i0 = aside ? (2*lane - 48) : (2*lane - 72);
            float ang0 = pos * __powf(10000.f, -(float)i0 / 24.f);
            float ang1 = pos * __powf(10000.f, -(float)(i0+1) / 24.f);
            float s0,c0,s1,c1;
            __sincosf(ang0, &s0, &c0);
            __sincosf(ang1, &s1, &c1);
            if (aside){
                qx = qx*c0 - qpx*s0;  qy = qy*c1 - qpy*s1;
                kx = kx*c0 - kpx*s0;  ky = ky*c1 - kpy*s1;
            } else {
                qx = qx*c0 + qpx*s0;  qy = qy*c1 + qpy*s1;
                kx = kx*c0 + kpx*s0;  ky = ky*c1 + kpy*s1;
            }
        }
        if (act){
            size_t o = ((size_t)h * NT_ + tok) * HD_ + d;
            Qg[o] = f2bf(qx); Qg[o+1] = f2bf(qy);
            Kg[o] = f2bf(kx); Kg[o+1] = f2bf(ky);
            Vg[o] = f2bf(vx); Vg[o+1] = f2bf(vy);
        }
    }
}

// ---------------------------------------------------------------- flash attention
__global__ __launch_bounds__(256) void attn_k(
    const u16* __restrict__ Qg, const u16* __restrict__ Kg,
    const u16* __restrict__ Vg, u16* __restrict__ Og)
{
    int h = blockIdx.y;
    int q0 = blockIdx.x * 64;
    __shared__ u16 Ks[64][104];
    __shared__ u16 Vt[96][72];
    __shared__ u16 Ps[4][16][72];
    int t = threadIdx.x, wave = t >> 6, lane = t & 63;
    int lrow = lane & 15, lgrp = lane >> 4;
    const float scale = 0.10206207261596577f;

    const u16* qbase = Qg + ((size_t)h * NT_ + q0 + wave*16 + lrow) * HD_;
    short8 qf[3];
    #pragma unroll
    for (int c = 0; c < 3; c++) qf[c] = *(const short8*)(qbase + c*32 + lgrp*8);

    float mr[4], lr[4];
    #pragma unroll
    for (int r = 0; r < 4; r++){ mr[r] = -1e30f; lr[r] = 0.f; }
    f32x4 oacc[6];
    #pragma unroll
    for (int n = 0; n < 6; n++) oacc[n] = (f32x4){0.f,0.f,0.f,0.f};

    int sr = t >> 2, sc4 = (t & 3) * 24;
    for (int kt = 0; kt < NT_/64; kt++){
        __syncthreads();
        {
            const u16* kp = Kg + ((size_t)h * NT_ + kt*64 + sr) * HD_ + sc4;
            uint4 a0 = *(const uint4*)kp;
            uint4 a1 = *(const uint4*)(kp + 8);
            uint4 a2 = *(const uint4*)(kp + 16);
            *(uint4*)&Ks[sr][sc4]      = a0;
            *(uint4*)&Ks[sr][sc4 + 8]  = a1;
            *(uint4*)&Ks[sr][sc4 + 16] = a2;
            const u16* vp = Vg + ((size_t)h * NT_ + kt*64 + sr) * HD_ + sc4;
            u16 vv[24];
            *(uint4*)&vv[0]  = *(const uint4*)vp;
            *(uint4*)&vv[8]  = *(const uint4*)(vp + 8);
            *(uint4*)&vv[16] = *(const uint4*)(vp + 16);
            #pragma unroll
            for (int j = 0; j < 24; j++) Vt[sc4 + j][sr] = vv[j];
        }
        __syncthreads();

        f32x4 s[4];
        #pragma unroll
        for (int nt = 0; nt < 4; nt++){
            s[nt] = (f32x4){0.f,0.f,0.f,0.f};
            #pragma unroll
            for (int c = 0; c < 3; c++){
                short8 kf = *(const short8*)&Ks[nt*16 + lrow][c*32 + lgrp*8];
                s[nt] = __builtin_amdgcn_mfma_f32_16x16x32_bf16(qf[c], kf, s[nt], 0,0,0);
            }
        }
        #pragma unroll
        for (int nt = 0; nt < 4; nt++) s[nt] *= scale;

        float mnew[4], corr[4];
        #pragma unroll
        for (int r = 0; r < 4; r++){
            float mt = fmaxf(fmaxf(s[0][r], s[1][r]), fmaxf(s[2][r], s[3][r]));
            for (int mask = 1; mask < 16; mask <<= 1)
                mt = fmaxf(mt, __shfl_xor(mt, mask));
            mnew[r] = fmaxf(mr[r], mt);
            corr[r] = __expf(mr[r] - mnew[r]);
            mr[r] = mnew[r];
        }
        float rs[4] = {0.f,0.f,0.f,0.f};
        #pragma unroll
        for (int nt = 0; nt < 4; nt++){
            #pragma unroll
            for (int r = 0; r < 4; r++){
                float p = __expf(s[nt][r] - mnew[r]);
                rs[r] += p;
                Ps[wave][lgrp*4 + r][nt*16 + lrow] = f2bf(p);
            }
        }
        #pragma unroll
        for (int r = 0; r < 4; r++){
            for (int mask = 1; mask < 16; mask <<= 1)
                rs[r] += __shfl_xor(rs[r], mask);
            lr[r] = lr[r] * corr[r] + rs[r];
        }
        #pragma unroll
        for (int n = 0; n < 6; n++)
            #pragma unroll
            for (int r = 0; r < 4; r++) oacc[n][r] *= corr[r];

        #pragma unroll
        for (int kc = 0; kc < 2; kc++){
            short8 pf = *(const short8*)&Ps[wave][lrow][kc*32 + lgrp*8];
            #pragma unroll
            for (int n = 0; n < 6; n++){
                short8 vf = *(const short8*)&Vt[n*16 + lrow][kc*32 + lgrp*8];
                oacc[n] = __builtin_amdgcn_mfma_f32_16x16x32_bf16(pf, vf, oacc[n], 0,0,0);
            }
        }
    }

    #pragma unroll
    for (int n = 0; n < 6; n++){
        #pragma unroll
        for (int r = 0; r < 4; r++){
            int tok = q0 + wave*16 + lgrp*4 + r;
            float ov = oacc[n][r] / lr[r];
            Og[(size_t)tok * D_ + h*HD_ + n*16 + lrow] = f2bf(ov);
        }
    }
}

// ---------------------------------------------------------------- launcher
extern "C" void kernel_launch(void* const* d_in, const int* in_sizes, int n_in,
                              void* d_out, int out_size, void* d_ws, size_t ws_size,
                              hipStream_t stream)
{
    const float* x        = (const float*)d_in[0];
    const float* y        = (const float*)d_in[1];
    const float* tt       = (const float*)d_in[2];
    const int*   pos      = (const int*)  d_in[3];
    const float* w_mod_x  = (const float*)d_in[4];
    const float* b_mod_x  = (const float*)d_in[5];
    const float* w_mod_y  = (const float*)d_in[6];
    const float* b_mod_y  = (const float*)d_in[7];
    const float* w_qkv_x  = (const float*)d_in[8];
    const float* b_qkv_x  = (const float*)d_in[9];
    const float* w_qkv_y  = (const float*)d_in[10];
    const float* b_qkv_y  = (const float*)d_in[11];
    const float* qn_x     = (const float*)d_in[12];
    const float* kn_x     = (const float*)d_in[13];
    const float* qn_y     = (const float*)d_in[14];
    const float* kn_y     = (const float*)d_in[15];
    const float* w_proj_x = (const float*)d_in[16];
    const float* b_proj_x = (const float*)d_in[17];
    const float* w_proj_y = (const float*)d_in[18];
    const float* b_proj_y = (const float*)d_in[19];
    const float* w1_x     = (const float*)d_in[20];
    const float* w2_x     = (const float*)d_in[21];
    const float* w3_x     = (const float*)d_in[22];
    const float* w1_y     = (const float*)d_in[23];
    const float* w2_y     = (const float*)d_in[24];
    const float* w3_y     = (const float*)d_in[25];
    float* dout = (float*)d_out;

    char* ws = (char*)d_ws;
    size_t off = 0;
    float* modx   = (float*)(ws + off); off += (size_t)(6*D_) * 4;
    float* mody   = (float*)(ws + off); off += (size_t)(6*D_) * 4;
    u16*   a      = (u16*)  (ws + off); off += (size_t)NT_ * D_ * 2;
    u16*   arena  = (u16*)  (ws + off); off += (size_t)2 * D_ * FF_ * 2;     // 37.75 MB
    u16*   r1     = (u16*)  (ws + off); off += (size_t)NT_ * FF_ * 2;        // qkvraw | hs
    u16*   r2     = (u16*)  (ws + off); off += (size_t)4 * H_ * NT_ * HD_ * 2; // QKV+Ob | hb
    float* x1     = (float*)(ws + off); off += (size_t)NT_ * D_ * 4;

    u16* qkvraw = r1;
    u16* hs     = r1;
    u16* Qb     = r2;
    u16* Kb     = r2 + (size_t)H_ * NT_ * HD_;
    u16* Vb     = r2 + (size_t)2 * H_ * NT_ * HD_;
    u16* Ob     = r2 + (size_t)3 * H_ * NT_ * HD_;
    u16* hb     = r2;

    const size_t qkvW  = (size_t)D_ * (3*D_);
    const size_t projW = (size_t)D_ * D_;
    const size_t ffW   = (size_t)D_ * FF_;

    // 1) modulation vectors + LN/mod1
    modvec_k<<<72, 256, 0, stream>>>(tt, w_mod_x, b_mod_x, w_mod_y, b_mod_y, modx, mody);
    lnmod_k<<<NT_, 256, 0, stream>>>(x, y, modx, mody, 0, a);
    // 2) qkv: transpose weights, merged GEMM -> qkvraw (bf16)
    transpose_k<<<dim3(48*144, 2), 256, 0, stream>>>(w_qkv_x, w_qkv_y, arena, arena + qkvW, D_, 3*D_);
    gemm2_k<0><<<18*36, 256, 0, stream>>>(a, arena, arena + qkvW, b_qkv_x, b_qkv_y,
        nullptr, nullptr, nullptr, nullptr, nullptr, nullptr, qkvraw, 3*D_, D_, 36);
    // 3) RMS + RoPE + reshape
    qkvpost_k<<<NT_, 256, 0, stream>>>(qkvraw, pos, qn_x, kn_x, qn_y, kn_y, Qb, Kb, Vb);
    // 4) attention
    attn_k<<<dim3(36, 16), 256, 0, stream>>>(Qb, Kb, Vb, Ob);
    // 5) proj + residual -> x1
    transpose_k<<<dim3(48*48, 2), 256, 0, stream>>>(w_proj_x, w_proj_y, arena, arena + projW, D_, D_);
    gemm2_k<1><<<18*12, 256, 0, stream>>>(Ob, arena, arena + projW, b_proj_x, b_proj_y,
        x, y - (size_t)NX_*D_, modx + 2*D_, mody + 2*D_, nullptr, x1, nullptr, D_, D_, 12);
    // 6) LN/mod2
    lnmod_k<<<NT_, 256, 0, stream>>>(x1, x1 + (size_t)NX_*D_, modx, mody, 3*D_, a);
    // 7) ffn w1 -> silu -> hs
    transpose_k<<<dim3(48*192, 2), 256, 0, stream>>>(w1_x, w1_y, arena, arena + ffW, D_, FF_);
    gemm2_k<2><<<18*48, 256, 0, stream>>>(a, arena, arena + ffW, nullptr, nullptr,
        nullptr, nullptr, nullptr, nullptr, nullptr, nullptr, hs, FF_, D_, 48);
    // 8) ffn w2 * hs -> hb
    transpose_k<<<dim3(48*192, 2), 256, 0, stream>>>(w2_x, w2_y, arena, arena + ffW, D_, FF_);
    gemm2_k<3><<<18*48, 256, 0, stream>>>(a, arena, arena + ffW, nullptr, nullptr,
        nullptr, nullptr, nullptr, nullptr, hs, nullptr, hb, FF_, D_, 48);
    // 9) ffn w3 + gate + residual -> d_out
    transpose_k<<<dim3(192*48, 2), 256, 0, stream>>>(w3_x, w3_y, arena, arena + ffW, FF_, D_);
    gemm2_k<4><<<18*12, 256, 0, stream>>>(hb, arena, arena + ffW, nullptr, nullptr,
        x1, x1, modx + 5*D_, mody + 5*D_, nullptr, dout, nullptr, D_, FF_, 12);
    (void)in_sizes; (void)n_in; (void)out_size; (void)ws_size;
}